// Round 14
// baseline (844.783 us; speedup 1.0000x reference)
//
#include <hip/hip_runtime.h>
#include <hip/hip_bf16.h>
#include <math.h>

#define B_   16
#define S_   4096
#define DIN  1024
#define V_   512
#define FOUT 120

typedef __attribute__((ext_vector_type(8))) short bf16x8;
typedef __attribute__((ext_vector_type(4))) float f32x4;

#define AS1 __attribute__((address_space(1)))
#define AS3 __attribute__((address_space(3)))

__device__ const float CSCALE = 0.1f / (64.0f * 4096.0f);
__device__ const float EPSF = 1e-5f;

__device__ inline void gl2lds16(const void* g, void* l) {
  __builtin_amdgcn_global_load_lds((const AS1 unsigned int*)g,
                                   (AS3 unsigned int*)l, 16, 0, 0);
}

// fp32 -> bf16 RNE
__device__ inline unsigned short f2b(float f) {
  unsigned u = __builtin_bit_cast(unsigned, f);
  unsigned r = (u + 0x7FFFu + ((u >> 16) & 1u)) >> 16;
  return (unsigned short)r;
}

__device__ inline bf16x8 pack8(float4 a, float4 b) {
  bf16x8 r;
  r[0] = (short)f2b(a.x); r[1] = (short)f2b(a.y);
  r[2] = (short)f2b(a.z); r[3] = (short)f2b(a.w);
  r[4] = (short)f2b(b.x); r[5] = (short)f2b(b.y);
  r[6] = (short)f2b(b.z); r[7] = (short)f2b(b.w);
  return r;
}

// Wt frag-major (r7-r12-verified): chunk e = ((ct*32 + k)*24 + f)*64 + l ; f = 3*nf + g
// lane l: channel ct*128 + nf*16 + (l&15), k-elem k*32 + (l>>4)*8
__global__ void msr_convw(const float* __restrict__ Wq, const float* __restrict__ Wk,
                          const float* __restrict__ Wv, unsigned short* __restrict__ Wt) {
  int e = blockIdx.x * 256 + threadIdx.x;
  int l = e & 63;
  int f = (e >> 6) % 24;
  int ck = (e >> 6) / 24;
  int k = ck & 31;
  int ct = ck >> 5;
  int nf = f / 3, g = f % 3;
  const float* W = (g == 0) ? Wq : (g == 1) ? Wk : Wv;
  int ch = ct * 128 + nf * 16 + (l & 15);
  const float* src = W + (size_t)ch * DIN + k * 32 + (l >> 4) * 8;
  float4 a = *(const float4*)src;
  float4 b = *(const float4*)(src + 4);
  *(bf16x8*)(Wt + (size_t)e * 8) = pack8(a, b);
}

// Xb = bf16(x), row-major [65536][1024] (r6-r12-verified)
__global__ __launch_bounds__(256) void msr_convx(const float* __restrict__ x,
                                                 unsigned short* __restrict__ Xb) {
  const size_t stride = (size_t)gridDim.x * 256;
  for (size_t i = blockIdx.x * 256ull + threadIdx.x; i < 8388608ull; i += stride) {
    const float* src = x + i * 8;
    float4 a = *(const float4*)src;
    float4 b = *(const float4*)(src + 4);
    *(bf16x8*)(Xb + i * 8) = pack8(a, b);
  }
}

#define WAITVM8  asm volatile("s_waitcnt vmcnt(8)" ::: "memory")
#define WAITVM6  asm volatile("s_waitcnt vmcnt(6)" ::: "memory")
#define WAITVM0  asm volatile("s_waitcnt vmcnt(0)" ::: "memory")
#define WAITLGKM asm volatile("s_waitcnt lgkmcnt(0)" ::: "memory")
#define SCHEDB   __builtin_amdgcn_sched_barrier(0)
#define BARRIER  { asm volatile("" ::: "memory"); __builtin_amdgcn_s_barrier(); asm volatile("" ::: "memory"); }

// Main: r12 skeleton (M=256, 3-buf, stage k+2, 1 barrier/step) with B moved
// OFF LDS to direct global->reg 1-step prefetch (r9-sub-proven path).
// BM=256 x 128ch x 3g, BK=32, 32 steps, 512 thr = 8 waves (2M x 4N).
// Wave tile 128r x 32ch x 3g: acc[3][8][2] = 192 AGPR; bE/bO 2x24 VGPR.
// LDS = 3 x 16KB (A only) = 48KB -> TWO blocks/CU (independent barrier domains).
// vmcnt invariant at step-k entry: in-flight = B(k)[6] + A(k+1)[2] = 8.
template <bool DIRECT>
__global__ __launch_bounds__(512, 2) void msr_main(
    const float* __restrict__ x, const unsigned short* __restrict__ Xb,
    const unsigned short* __restrict__ Wt, float* __restrict__ outacc) {
  const int bid = blockIdx.x;
  const int xcd = bid & 7;
  const int j = bid >> 3;               // 0..127 per-XCD order
  const int ct = j & 3;                 // ct fastest: same rt 4x consecutive (L2-hot x)
  const int rt = xcd * 32 + (j >> 2);   // 0..255, bijective (r12-verified)
  const int r0 = rt << 8;

  __shared__ __align__(16) unsigned char smem_[49152];  // 3 bufs x A 16KB

  const int t = threadIdx.x;
  const int w = t >> 6, lane = t & 63;
  const int l16 = lane * 16;
  const int amb = (w >> 2) * 8192;      // A m-frag base (bytes)

  // B direct-to-reg (r9-sub-verified): wave group (w&3) reads frags 6*(w&3)..+5;
  // step k at +k*12288 shorts; frag i at +i*512.
  const unsigned short* pB =
      Wt + (((size_t)ct * 32) * 24 + 6 * (w & 3)) * 512 + (size_t)lane * 8;

  // A staging (r12-verified): wave w stages chunks {w, 8+w}; pre-swizzled source,
  // linear LDS dest (base + lane*16).
  const unsigned short* srcA0 =
      Xb + (size_t)(r0 + w * 16 + (lane & 15)) * DIN + ((lane >> 4) << 3);
  const unsigned short* srcA1 = srcA0 + (size_t)128 * DIN;
  const float* pXf = x + (size_t)(r0 + w * 16 + (lane & 15)) * DIN + ((lane >> 4) << 3);

  f32x4 acc[3][8][2];
#pragma unroll
  for (int g = 0; g < 3; ++g)
#pragma unroll
    for (int m = 0; m < 8; ++m)
#pragma unroll
      for (int n = 0; n < 2; ++n) acc[g][m][n] = (f32x4){0.f, 0.f, 0.f, 0.f};

  bf16x8 bE[6], bO[6];

#define STAGEA(KK, SB) { \
  unsigned char* _sb = smem_ + (SB) * 16384; \
  if constexpr (DIRECT) { \
    gl2lds16(srcA0 + (size_t)(KK) * 32, _sb + w * 1024); \
    gl2lds16(srcA1 + (size_t)(KK) * 32, _sb + (8 + w) * 1024); \
  } else { \
    const float* _p0 = pXf + (size_t)(KK) * 32; \
    const float* _p1 = _p0 + (size_t)128 * DIN; \
    *(bf16x8*)(_sb + (w * 64 + lane) * 16) = \
        pack8(*(const float4*)_p0, *(const float4*)(_p0 + 4)); \
    *(bf16x8*)(_sb + ((8 + w) * 64 + lane) * 16) = \
        pack8(*(const float4*)_p1, *(const float4*)(_p1 + 4)); \
  } }

#define LOADB(dst, KK) { \
  const unsigned short* _pb = pB + (size_t)(KK) * 12288; \
  _Pragma("unroll") for (int i = 0; i < 6; ++i) \
    dst[i] = *(const bf16x8*)(_pb + i * 512); }

#define COMPUTE(KB, BF) { \
  const unsigned char* _kb = smem_ + (KB) * 16384; \
  __builtin_amdgcn_s_setprio(1); \
  _Pragma("unroll") for (int m = 0; m < 8; ++m) { \
    bf16x8 _afr = *(const bf16x8*)(_kb + amb + m * 1024 + l16); \
    _Pragma("unroll") for (int g = 0; g < 3; ++g) { \
      acc[g][m][0] = __builtin_amdgcn_mfma_f32_16x16x32_bf16(_afr, BF[g],     acc[g][m][0], 0, 0, 0); \
      acc[g][m][1] = __builtin_amdgcn_mfma_f32_16x16x32_bf16(_afr, BF[3 + g], acc[g][m][1], 0, 0, 0); \
    } \
  } \
  __builtin_amdgcn_s_setprio(0); }

// step KK (buf KB=KK%3): prefetch B(KK+1)->NXT; stage A(KK+2)->SB=(KK+2)%3;
// compute CUR; retire A(KK+1) via counted vmcnt; barrier.
#define STEP(KB, SB, KK, CUR, NXT) { \
  LOADB(NXT, (KK) + 1); \
  STAGEA((KK) + 2, SB); \
  SCHEDB; \
  COMPUTE(KB, CUR); \
  if constexpr (DIRECT) { WAITVM8; } else { WAITLGKM; } \
  BARRIER; }

  // ---- prologue: A(0)->buf0, A(1)->buf1, B(0)->bE ----
  STAGEA(0, 0);
  STAGEA(1, 1);
  LOADB(bE, 0);
  if constexpr (DIRECT) { WAITVM8; } else { WAITLGKM; }  // A(0) landed
  BARRIER;

  // ---- steps 0..29: 5 iters x 6 steps (buf k%3; B regs alternate E/O) ----
#pragma unroll 1
  for (int i = 0; i < 5; ++i) {
    const int k6 = i * 6;
    STEP(0, 2, k6,     bE, bO);
    STEP(1, 0, k6 + 1, bO, bE);
    STEP(2, 1, k6 + 2, bE, bO);
    STEP(0, 2, k6 + 3, bO, bE);
    STEP(1, 0, k6 + 4, bE, bO);
    STEP(2, 1, k6 + 5, bO, bE);
  }
  // ---- step 30 (buf 0): load B(31); no stage; retire A(31) via vmcnt(6) ----
  LOADB(bO, 31);
  SCHEDB;
  COMPUTE(0, bE);
  if constexpr (DIRECT) { WAITVM6; } else { WAITLGKM; }
  BARRIER;
  // ---- step 31 (buf 1): compute only (compiler waits B(31) regs) ----
  COMPUTE(1, bO);
#undef STEP
#undef COMPUTE
#undef LOADB
#undef STAGEA

  // ---- epilogue (r12-verified): p = (q*k)[c^1]*v[c]; fold rows; atomicAdd ----
  float pd0 = 0.f, pd1 = 0.f;
#pragma unroll
  for (int m = 0; m < 8; ++m)
#pragma unroll
    for (int r = 0; r < 4; ++r) {
      float qk0 = acc[0][m][0][r] * acc[1][m][0][r];
      float qk1 = acc[0][m][1][r] * acc[1][m][1][r];
      pd0 += __shfl_xor(qk0, 1, 64) * acc[2][m][0][r];
      pd1 += __shfl_xor(qk1, 1, 64) * acc[2][m][1][r];
    }
  pd0 += __shfl_xor(pd0, 16, 64); pd0 += __shfl_xor(pd0, 32, 64);
  pd1 += __shfl_xor(pd1, 16, 64); pd1 += __shfl_xor(pd1, 32, 64);

  // rows r0..r0+255 in h-block rt>>1 ; d = ((w&3)*32 + n*16 + (lane&15)) % 64
  if (lane < 16) {
    float* dst = &outacc[((rt >> 1) << 6) + (w & 1) * 32 + lane];
    atomicAdd(dst, pd0);
    atomicAdd(dst + 16, pd1);
  }
}

// Finish: per-batch RMSNorm -> exact gelu -> @ Wout.T (verified r1-r12)
__global__ __launch_bounds__(256) void msr_finish(
    const float* __restrict__ outacc, const float* __restrict__ gamma,
    const float* __restrict__ Wout, float* __restrict__ y) {
  const int b = blockIdx.x;
  const int t = threadIdx.x;
  __shared__ float g[V_];
  __shared__ float wsum[4];

  float v0 = outacc[b * V_ + t] * CSCALE;
  float v1 = outacc[b * V_ + 256 + t] * CSCALE;
  float ss = v0 * v0 + v1 * v1;
#pragma unroll
  for (int o = 32; o > 0; o >>= 1) ss += __shfl_down(ss, o, 64);
  if ((t & 63) == 0) wsum[t >> 6] = ss;
  __syncthreads();
  float tot = wsum[0] + wsum[1] + wsum[2] + wsum[3];
  float rs = rsqrtf(tot * (1.0f / (float)V_) + EPSF);

  float r0v = v0 * rs * gamma[t];
  float r1v = v1 * rs * gamma[t + 256];
  g[t]       = 0.5f * r0v * (1.0f + erff(r0v * 0.70710678118654752f));
  g[t + 256] = 0.5f * r1v * (1.0f + erff(r1v * 0.70710678118654752f));
  __syncthreads();

  if (t < FOUT) {
    const float* wr = Wout + (size_t)t * V_;
    float acc = 0.f;
#pragma unroll 4
    for (int c = 0; c < V_; c += 4) {
      float4 w4 = *(const float4*)(wr + c);
      acc += g[c] * w4.x + g[c + 1] * w4.y + g[c + 2] * w4.z + g[c + 3] * w4.w;
    }
    y[b * FOUT + t] = acc;
  }
}

extern "C" void kernel_launch(void* const* d_in, const int* in_sizes, int n_in,
                              void* d_out, int out_size, void* d_ws, size_t ws_size,
                              hipStream_t stream) {
  const float* x     = (const float*)d_in[0];
  const float* Wq    = (const float*)d_in[1];
  const float* Wk    = (const float*)d_in[2];
  const float* Wv    = (const float*)d_in[3];
  const float* Wout  = (const float*)d_in[4];
  const float* gamma = (const float*)d_in[5];

  float* outacc = (float*)d_ws;                                    // 32 KB
  unsigned short* Wt = (unsigned short*)((char*)d_ws + 32768);     // 3 MB
  unsigned short* Xb = (unsigned short*)((char*)d_ws + 32768 + 3145728);  // 128 MB
  float* y = (float*)d_out;

  const size_t need = 32768ull + 3145728ull + 134217728ull;

  msr_convw<<<768, 256, 0, stream>>>(Wq, Wk, Wv, Wt);
  hipMemsetAsync(outacc, 0, B_ * V_ * sizeof(float), stream);

  if (ws_size >= need) {
    msr_convx<<<2048, 256, 0, stream>>>(x, Xb);
    msr_main<true><<<1024, 512, 0, stream>>>(x, Xb, Wt, outacc);
  } else {
    msr_main<false><<<1024, 512, 0, stream>>>(x, Xb, Wt, outacc);
  }
  msr_finish<<<B_, 256, 0, stream>>>(outacc, gamma, Wout, y);
}